// Round 4
// baseline (826.793 us; speedup 1.0000x reference)
//
#include <hip/hip_runtime.h>

#define BATCHN 131072
#define FD 512
#define F2 256
#define NOBJ 100000
#define NPRED 2000
#define LDSTR 520   // bf16 tile row stride (conflict-free b128 reads, verified)

typedef __bf16 bf16x8 __attribute__((ext_vector_type(8)));
typedef float f32x4 __attribute__((ext_vector_type(4)));

__device__ __forceinline__ ushort f2bf(float f) {
  union { float f; uint u; } c; c.f = f;
  uint u = c.u;
  u += 0x7FFFu + ((u >> 16) & 1u);   // RNE
  return (ushort)(u >> 16);
}

// ---------------- ws layout (float units) ----------------
// cnt (int): subj[100000], obj[100000], predi[2000] at 0 / 100000 / 200000
#define WS_STATS123 202752   // 3*1024: per-e [sum512, sumsq512]
#define WS_S4       205824   // 64 slots * [sum256, sumsq256]
#define WS_SCSH123  238592   // 3*1024
#define WS_SCSH4    241664   // 512
#define WS_W4BF     242176   // ushort[256*512] = 65536 floats
#define WS_A1       307712   // bf16[100000*256] = 12.8M floats
#define WS_A2       13107712 // bf16[100000*256]
#define WS_A3       25907712 // bf16[2000*256] = 256000 floats
#define WS_H        26163712 // bf16[131072*256] = 16777216 floats
// end: 42,940,928 floats = ~172 MB

// ---------------- histogram of indices ----------------
__global__ __launch_bounds__(256) void k_hist(
    const int* __restrict__ subj, const int* __restrict__ obj,
    const int* __restrict__ predi, int* __restrict__ cnt)
{
  int b = blockIdx.x * 256 + threadIdx.x;
  atomicAdd(&cnt[subj[b]], 1);
  atomicAdd(&cnt[NOBJ + obj[b]], 1);
  atomicAdd(&cnt[2 * NOBJ + predi[b]], 1);
}

// ---------------- BN1/2/3 stats: weighted sequential scan, STATIC pipelined ----------------
// sum_b W[idx_b][f] = sum_i cnt[i]*W[i][f]; cnt==0 rows multiply by 0 (load anyway: latency >> BW)
#define NB1 782   // ceil(100000/128)
#define NB3 16    // ceil(2000/128)
#define NB_SCAN (NB1 + NB1 + NB3)
__global__ __launch_bounds__(256) void k_scan123(
    const float* __restrict__ W1, const float* __restrict__ W2,
    const float* __restrict__ W3, const int* __restrict__ cnt,
    float* __restrict__ stats)
{
  int blk = blockIdx.x;
  int e, rowBase, N;
  if (blk < NB1)            { e = 0; rowBase = blk * 128;           N = NOBJ; }
  else if (blk < 2 * NB1)   { e = 1; rowBase = (blk - NB1) * 128;   N = NOBJ; }
  else                      { e = 2; rowBase = (blk - 2*NB1) * 128; N = NPRED; }
  const float* W = (e == 0) ? W1 : (e == 1 ? W2 : W3);
  const int* cn = cnt + (e == 0 ? 0 : (e == 1 ? NOBJ : 2 * NOBJ));

  __shared__ float wL[128];
  __shared__ float redS[512], redQ[512];
  int t = threadIdx.x;
  if (t < 128) { int r = rowBase + t; wL[t] = (r < N) ? (float)cn[r] : 0.f; }
  redS[t] = 0.f; redS[t + 256] = 0.f; redQ[t] = 0.f; redQ[t + 256] = 0.f;
  __syncthreads();

  int c = t & 63, rg = t >> 6;   // lane c -> feats [8c, 8c+8); wave covers full 2KB row
  float s[8], q[8];
  #pragma unroll
  for (int j = 0; j < 8; ++j) { s[j] = 0.f; q[j] = 0.f; }

  #pragma unroll 8
  for (int r = rg; r < 128; r += 4) {
    int gr = rowBase + r; if (gr >= N) gr = N - 1;   // clamp tail (weight is 0 there)
    const float* row = W + (size_t)gr * FD + c * 8;
    float4 va = *(const float4*)(row);
    float4 vb = *(const float4*)(row + 4);
    float w = wL[r];
    float x[8] = {va.x, va.y, va.z, va.w, vb.x, vb.y, vb.z, vb.w};
    #pragma unroll
    for (int j = 0; j < 8; ++j) { float wx = w * x[j]; s[j] += wx; q[j] = fmaf(wx, x[j], q[j]); }
  }

  #pragma unroll
  for (int j = 0; j < 8; ++j) {
    atomicAdd(&redS[c * 8 + j], s[j]);
    atomicAdd(&redQ[c * 8 + j], q[j]);
  }
  __syncthreads();
  float* se = stats + e * 1024;
  atomicAdd(&se[t],        redS[t]);
  atomicAdd(&se[t + 256],  redS[t + 256]);
  atomicAdd(&se[512 + t],  redQ[t]);
  atomicAdd(&se[768 + t],  redQ[t + 256]);
}

__global__ void k_fin123(const float* __restrict__ stats,
                         const float* __restrict__ g1, const float* __restrict__ be1,
                         const float* __restrict__ g2, const float* __restrict__ be2,
                         const float* __restrict__ g3, const float* __restrict__ be3,
                         float* __restrict__ scsh)
{
  int e = blockIdx.x, f = threadIdx.x;  // 3 x 512
  const float* g  = (e == 0) ? g1  : (e == 1 ? g2  : g3);
  const float* be = (e == 0) ? be1 : (e == 1 ? be2 : be3);
  float S = stats[e * 1024 + f], SS = stats[e * 1024 + 512 + f];
  const float invB = 1.f / (float)BATCHN;
  float mean = S * invB;
  float var  = SS * invB - mean * mean;
  if (!(var >= 0.f && var < 1e30f)) var = 1.f;
  if (!(mean > -1e30f && mean < 1e30f)) mean = 0.f;
  float r = rsqrtf(var + 1e-5f);
  float sc = g[f] * r;
  scsh[e * 1024 + f]       = sc;
  scsh[e * 1024 + 512 + f] = be[f] - mean * sc;
}

// ---------------- W4 fp32 -> bf16 ----------------
__global__ __launch_bounds__(256) void k_convW4(const float* __restrict__ W4,
                                                ushort* __restrict__ w4bf)
{
  int i = (blockIdx.x * 256 + threadIdx.x) * 4;
  float4 v = *(const float4*)(W4 + i);
  ushort4 o = {f2bf(v.x), f2bf(v.y), f2bf(v.z), f2bf(v.w)};
  *(ushort4*)(w4bf + i) = o;
}

// ---------------- A_e = relu(bn_e(W_e)) @ W4^T per table row; STATIC-pipelined phase A ----------------
// Dead rows (cnt==0 / tail) carry garbage through the tile; MFMA row r of C depends only on
// tile row r, and dead rows are never written out — so no zero-fill needed.
#define NB_A1 3125  // 100000/32
#define NB_A3 63    // ceil(2000/32)
#define NB_BUILD (NB_A1 + NB_A1 + NB_A3)
__global__ __launch_bounds__(256) void k_buildA(
    const float* __restrict__ W1, const float* __restrict__ W2,
    const float* __restrict__ W3, const ushort* __restrict__ w4bf,
    const int* __restrict__ cnt, const float* __restrict__ scsh,
    ushort* __restrict__ A1, ushort* __restrict__ A2, ushort* __restrict__ A3)
{
  alignas(16) __shared__ ushort tileL[32 * LDSTR];  // 33,280 B; reused as bf16 bounce [32][268]
  int blk = blockIdx.x;
  int e, rowBase, N; const float* W; ushort* A; const int* cn;
  if (blk < NB_A1)          { e = 0; rowBase = blk * 32;             N = NOBJ;  W = W1; A = A1; cn = cnt; }
  else if (blk < 2 * NB_A1) { e = 1; rowBase = (blk - NB_A1) * 32;   N = NOBJ;  W = W2; A = A2; cn = cnt + NOBJ; }
  else                      { e = 2; rowBase = (blk - 2*NB_A1) * 32; N = NPRED; W = W3; A = A3; cn = cnt + 2 * NOBJ; }

  int t = threadIdx.x;
  int c = t & 63, rg = t >> 6;
  int w = t >> 6, lane = t & 63, m = lane & 15, q = lane >> 4;

  // phase A: stage all 8 rows (16 loads in flight), then convert+store
  float4 va[8], vb[8];
  #pragma unroll
  for (int u = 0; u < 8; ++u) {
    int gr = rowBase + rg + 4 * u;
    if (gr >= N) gr = N - 1;          // tail clamp (e==2 only); row unused downstream
    const float* row = W + (size_t)gr * FD + c * 8;
    va[u] = *(const float4*)(row);
    vb[u] = *(const float4*)(row + 4);
  }
  // prefetch first B-operand fragments while phase-A loads are in flight
  const ushort* w4p = w4bf + ((size_t)(64 * w + m)) * FD + q * 8;
  bf16x8 bc0 = *(const bf16x8*)(w4p + 0 * 16 * FD);
  bf16x8 bc1 = *(const bf16x8*)(w4p + 1 * 16 * FD);
  bf16x8 bc2 = *(const bf16x8*)(w4p + 2 * 16 * FD);
  bf16x8 bc3 = *(const bf16x8*)(w4p + 3 * 16 * FD);

  float sc[8], sh[8];
  #pragma unroll
  for (int j = 0; j < 8; ++j) {
    sc[j] = scsh[e * 1024 + c * 8 + j];
    sh[j] = scsh[e * 1024 + 512 + c * 8 + j];
  }

  #pragma unroll
  for (int u = 0; u < 8; ++u) {
    int r = rg + 4 * u;
    float x[8] = {va[u].x, va[u].y, va[u].z, va[u].w, vb[u].x, vb[u].y, vb[u].z, vb[u].w};
    union { ushort o[8]; uint4 v; } uu;
    #pragma unroll
    for (int j = 0; j < 8; ++j) {
      float v = fmaxf(fmaf(sc[j], x[j], sh[j]), 0.f);
      v = fminf(v, 60000.f);
      uu.o[j] = f2bf(v);
    }
    *(uint4*)&tileL[r * LDSTR + c * 8] = uu.v;
  }
  __syncthreads();

  // phase B: 32x256x512 MFMA, B software-pipelined
  f32x4 acc[2][4];
  #pragma unroll
  for (int mi = 0; mi < 2; ++mi)
    #pragma unroll
    for (int ni = 0; ni < 4; ++ni)
      acc[mi][ni] = (f32x4){0.f, 0.f, 0.f, 0.f};
  const ushort* fpL = tileL + m * LDSTR + q * 8;

  for (int kk = 0; kk < 16; ++kk) {
    int kc = kk * 32;
    bf16x8 af0 = *(const bf16x8*)(fpL + kc);
    bf16x8 af1 = *(const bf16x8*)(fpL + 16 * LDSTR + kc);
    bf16x8 bn0, bn1, bn2, bn3;
    if (kk < 15) {
      int kn = kc + 32;
      bn0 = *(const bf16x8*)(w4p + 0 * 16 * FD + kn);
      bn1 = *(const bf16x8*)(w4p + 1 * 16 * FD + kn);
      bn2 = *(const bf16x8*)(w4p + 2 * 16 * FD + kn);
      bn3 = *(const bf16x8*)(w4p + 3 * 16 * FD + kn);
    }
    acc[0][0] = __builtin_amdgcn_mfma_f32_16x16x32_bf16(af0, bc0, acc[0][0], 0, 0, 0);
    acc[1][0] = __builtin_amdgcn_mfma_f32_16x16x32_bf16(af1, bc0, acc[1][0], 0, 0, 0);
    acc[0][1] = __builtin_amdgcn_mfma_f32_16x16x32_bf16(af0, bc1, acc[0][1], 0, 0, 0);
    acc[1][1] = __builtin_amdgcn_mfma_f32_16x16x32_bf16(af1, bc1, acc[1][1], 0, 0, 0);
    acc[0][2] = __builtin_amdgcn_mfma_f32_16x16x32_bf16(af0, bc2, acc[0][2], 0, 0, 0);
    acc[1][2] = __builtin_amdgcn_mfma_f32_16x16x32_bf16(af1, bc2, acc[1][2], 0, 0, 0);
    acc[0][3] = __builtin_amdgcn_mfma_f32_16x16x32_bf16(af0, bc3, acc[0][3], 0, 0, 0);
    acc[1][3] = __builtin_amdgcn_mfma_f32_16x16x32_bf16(af1, bc3, acc[1][3], 0, 0, 0);
    bc0 = bn0; bc1 = bn1; bc2 = bn2; bc3 = bn3;
  }
  __syncthreads();  // done reading tileL as bf16 tile

  // bounce acc -> LDS bf16 [32][268] (row stride 268: q-rows land on distinct banks)
  ushort* ldsB = (ushort*)tileL;
  #pragma unroll
  for (int mi = 0; mi < 2; ++mi)
    #pragma unroll
    for (int ni = 0; ni < 4; ++ni)
      #pragma unroll
      for (int rr = 0; rr < 4; ++rr)
        ldsB[(16 * mi + 4 * q + rr) * 268 + 64 * w + 16 * ni + m] = f2bf(acc[mi][ni][rr]);
  __syncthreads();
  int hr = t >> 7, p = (t & 127) * 2;   // 2 rows per pass; thread -> 2 bf16 -> 1 uint
  #pragma unroll
  for (int r = 0; r < 32; r += 2) {
    int rr = r + hr;
    int gr = rowBase + rr;
    if (gr < N && cn[gr] != 0)
      *(uint*)&A[(size_t)gr * F2 + p] = *(const uint*)&ldsB[rr * 268 + p];
  }
}

// ---------------- BN4 stats of h = A1[s]+A2[o]+A3[p]; also materialize h (bf16) ----------------
__global__ __launch_bounds__(256) void k_hstats(
    const int* __restrict__ subj, const int* __restrict__ obj,
    const int* __restrict__ predi,
    const ushort* __restrict__ A1, const ushort* __restrict__ A2,
    const ushort* __restrict__ A3, ushort* __restrict__ h,
    float* __restrict__ s4)
{
  __shared__ float colS[256], colQ[256];
  int t = threadIdx.x;
  colS[t] = 0.f; colQ[t] = 0.f;
  __syncthreads();
  int c = t & 31;       // lane c -> cols [8c, 8c+8); 32 lanes cover one 512B bf16 row
  int pair = t >> 5;    // 8 half-waves, one sample each per iter
  float ls[8], lq[8];
  #pragma unroll
  for (int j = 0; j < 8; ++j) { ls[j] = 0.f; lq[j] = 0.f; }
  int base = blockIdx.x * 64;
  #pragma unroll 4
  for (int i = 0; i < 8; ++i) {
    int b = base + i * 8 + pair;
    bf16x8 v1 = *(const bf16x8*)(A1 + (size_t)subj[b]  * F2 + c * 8);
    bf16x8 v2 = *(const bf16x8*)(A2 + (size_t)obj[b]   * F2 + c * 8);
    bf16x8 v3 = *(const bf16x8*)(A3 + (size_t)predi[b] * F2 + c * 8);
    union { ushort o[8]; uint4 v; } u;
    #pragma unroll
    for (int j = 0; j < 8; ++j) {
      float hv = (float)v1[j] + (float)v2[j] + (float)v3[j];
      ls[j] += hv; lq[j] = fmaf(hv, hv, lq[j]);
      u.o[j] = f2bf(hv);
    }
    *(uint4*)&h[(size_t)b * F2 + c * 8] = u.v;
  }
  #pragma unroll
  for (int j = 0; j < 8; ++j) {
    atomicAdd(&colS[c * 8 + j], ls[j]);
    atomicAdd(&colQ[c * 8 + j], lq[j]);
  }
  __syncthreads();
  int slot = blockIdx.x & 63;
  atomicAdd(&s4[slot * 512 + t],       colS[t]);
  atomicAdd(&s4[slot * 512 + 256 + t], colQ[t]);
}

__global__ void k_fin4(const float* __restrict__ s4, const float* __restrict__ g4,
                       const float* __restrict__ be4, float* __restrict__ scsh4)
{
  int j = threadIdx.x;  // 256
  float S = 0.f, SS = 0.f;
  for (int sl = 0; sl < 64; ++sl) { S += s4[sl * 512 + j]; SS += s4[sl * 512 + 256 + j]; }
  const float invB = 1.f / (float)BATCHN;
  float mean = S * invB;
  float var  = SS * invB - mean * mean;
  if (!(var >= 0.f && var < 1e30f)) var = 1.f;
  if (!(mean > -1e30f && mean < 1e30f)) mean = 0.f;
  float r = rsqrtf(var + 1e-5f);
  float sc = g4[j] * r;
  scsh4[j]       = sc;
  scsh4[256 + j] = be4[j] - mean * sc;
}

// ---------------- final: stream h (bf16), BN4+relu+dot(W5)+b5 -> logits ----------------
__global__ __launch_bounds__(256) void k_final(
    const ushort* __restrict__ h, const float* __restrict__ scsh4,
    const float* __restrict__ W5, const float* __restrict__ b5,
    float* __restrict__ out)
{
  int t = threadIdx.x;
  int c = t & 31, pair = t >> 5;
  float sc4v[8], sh4v[8], w5v[8];
  #pragma unroll
  for (int j = 0; j < 8; ++j) {
    int col = c * 8 + j;
    sc4v[j] = scsh4[col];
    sh4v[j] = scsh4[256 + col];
    w5v[j]  = W5[col];
  }
  float bb = b5[0];
  int base = blockIdx.x * 64;
  #pragma unroll 4
  for (int i = 0; i < 8; ++i) {
    int b = base + i * 8 + pair;
    bf16x8 hv = *(const bf16x8*)(h + (size_t)b * F2 + c * 8);
    float acc = 0.f;
    #pragma unroll
    for (int j = 0; j < 8; ++j)
      acc += fmaxf(fmaf(sc4v[j], (float)hv[j], sh4v[j]), 0.f) * w5v[j];
    #pragma unroll
    for (int off = 1; off < 32; off <<= 1)
      acc += __shfl_xor(acc, off, 64);
    if (c == 0) out[b] = acc + bb;
  }
}

extern "C" void kernel_launch(void* const* d_in, const int* in_sizes, int n_in,
                              void* d_out, int out_size, void* d_ws, size_t ws_size,
                              hipStream_t stream)
{
  const int* subj  = (const int*)d_in[0];
  const int* obj   = (const int*)d_in[1];
  const int* predi = (const int*)d_in[2];
  const float* W1  = (const float*)d_in[3];
  // b1/b2/b3/b4 cancel inside their BatchNorms — never read
  const float* g1  = (const float*)d_in[5];
  const float* be1 = (const float*)d_in[6];
  const float* W2  = (const float*)d_in[7];
  const float* g2  = (const float*)d_in[9];
  const float* be2 = (const float*)d_in[10];
  const float* W3  = (const float*)d_in[11];
  const float* g3  = (const float*)d_in[13];
  const float* be3 = (const float*)d_in[14];
  const float* W4  = (const float*)d_in[15];
  const float* g4  = (const float*)d_in[17];
  const float* be4 = (const float*)d_in[18];
  const float* W5  = (const float*)d_in[19];
  const float* b5  = (const float*)d_in[20];

  float* wsf   = (float*)d_ws;
  int*   cnt   = (int*)d_ws;
  ushort* w4bf = (ushort*)(wsf + WS_W4BF);
  ushort* A1   = (ushort*)(wsf + WS_A1);
  ushort* A2   = (ushort*)(wsf + WS_A2);
  ushort* A3   = (ushort*)(wsf + WS_A3);
  ushort* hbuf = (ushort*)(wsf + WS_H);
  float* out   = (float*)d_out;

  hipMemsetAsync(d_ws, 0, WS_SCSH123 * 4, stream);  // zero cnt + stats123 + s4
  k_hist<<<BATCHN / 256, 256, 0, stream>>>(subj, obj, predi, cnt);
  k_convW4<<<128, 256, 0, stream>>>(W4, w4bf);
  k_scan123<<<NB_SCAN, 256, 0, stream>>>(W1, W2, W3, cnt, wsf + WS_STATS123);
  k_fin123<<<3, 512, 0, stream>>>(wsf + WS_STATS123, g1, be1, g2, be2, g3, be3, wsf + WS_SCSH123);
  k_buildA<<<NB_BUILD, 256, 0, stream>>>(W1, W2, W3, w4bf, cnt, wsf + WS_SCSH123, A1, A2, A3);
  k_hstats<<<BATCHN / 64, 256, 0, stream>>>(subj, obj, predi, A1, A2, A3, hbuf, wsf + WS_S4);
  k_fin4<<<1, 256, 0, stream>>>(wsf + WS_S4, g4, be4, wsf + WS_SCSH4);
  k_final<<<BATCHN / 64, 256, 0, stream>>>(hbuf, wsf + WS_SCSH4, W5, b5, out);
}